// Round 15
// baseline (22778.665 us; speedup 1.0000x reference)
//
#include <hip/hip_runtime.h>
#include <hip/hip_bf16.h>
#include <math.h>

// Problem config (fixed)
#define BB 32      // batch
#define TT 128     // time steps
#define UU 1024    // units
#define MM 8       // memory slots
#define LL 9       // M+1
#define RR 17      // 2M+1
#define MROWS 288  // BB*LL
#define RSC 4096.0f          // residual plane scale (2^12)
#define RSCI (1.0f/4096.0f)

typedef _Float16 f16x8 __attribute__((ext_vector_type(8)));
typedef float f32x4 __attribute__((ext_vector_type(4)));
typedef float f32x8 __attribute__((ext_vector_type(8)));

// fp16 split-2 with scaled residual: v ~= h1 + h2/4096, |err| <= 2^-22|v|
__device__ __forceinline__ void split2(float v, _Float16* h1, _Float16* h2)
{
    _Float16 a = (_Float16)v;
    float r = (v - (float)a) * RSC;
    *h1 = a; *h2 = (_Float16)r;
}

__device__ __forceinline__ void split2x8(const f32x8 v, f16x8& a, f16x8& b)
{
#pragma unroll
    for (int j = 0; j < 8; ++j) {
        float f = v[j];
        _Float16 h1 = (_Float16)f;
        float r = (f - (float)h1) * RSC;
        a[j] = h1; b[j] = (_Float16)r;
    }
}

__device__ __forceinline__ float gelu_f(float x)
{
    float t = tanhf(0.7978845608028654f * (x + 0.044715f * x * x * x));
    return 0.5f * x * (1.f + t);
}

// ================= K-split fp16-split2 MFMA GEMM (R11/R13 arithmetic) =======
// Partial[ks][MROWS][N] = A[MROWS, kslice] @ Bt[N, kslice]^T, kslice = KLEN.
// accM += a1*b1 ; accR += a1*b2s + a2s*b1 ; result = accM + accR/4096.
// R13's pipelined schedule; MFMA order identical to R11 (bit-identical).
template<int CG, int NKS, int KLEN>
__global__ __launch_bounds__(256) void gemmks(
    const float* __restrict__ A,
    const _Float16* __restrict__ B1, const _Float16* __restrict__ B2,
    float* __restrict__ P, int N, int GdivP)
{
    static_assert(KLEN % 128 == 0, "pipeline processes chunk pairs");
    int tid = threadIdx.x, wave = tid >> 6, lane = tid & 63;
    int bid = blockIdx.x;
    int x = bid & 7, inner = bid >> 3;
    int q = inner % GdivP, rowT = inner / GdivP;
    int g = x + 8 * q;
    int colT = g / NKS, ks = g % NKS;

    int lr = lane & 15, kg = lane >> 4;
    int row0 = rowT * 32 + (wave & 1) * 16;
    int col0 = colT * (CG * 32) + (wave >> 1) * (CG * 16);
    int kbase = ks * KLEN;

    const float* Ap = A + (size_t)(row0 + lr) * 1024 + kbase + kg * 8;
    size_t boff = (size_t)(col0 + lr) * 1024 + kbase + kg * 8;

    f32x4 accM[CG], accR[CG];
#pragma unroll
    for (int c = 0; c < CG; ++c) {
        accM[c] = (f32x4){0.f, 0.f, 0.f, 0.f};
        accR[c] = (f32x4){0.f, 0.f, 0.f, 0.f};
    }

    f32x8 afA0, afA1, afB0, afB1;
    f16x8 bvA[2][CG][2], bvB[2][CG][2];

    auto loadChunkA = [&](int kc) {
        afA0 = *(const f32x8*)(Ap + kc);
        afA1 = *(const f32x8*)(Ap + kc + 32);
#pragma unroll
        for (int h = 0; h < 2; ++h)
#pragma unroll
            for (int c = 0; c < CG; ++c) {
                size_t o = boff + (size_t)c * 16 * 1024 + kc + h * 32;
                bvA[h][c][0] = *(const f16x8*)(B1 + o);
                bvA[h][c][1] = *(const f16x8*)(B2 + o);
            }
    };
    auto loadChunkB = [&](int kc) {
        afB0 = *(const f32x8*)(Ap + kc);
        afB1 = *(const f32x8*)(Ap + kc + 32);
#pragma unroll
        for (int h = 0; h < 2; ++h)
#pragma unroll
            for (int c = 0; c < CG; ++c) {
                size_t o = boff + (size_t)c * 16 * 1024 + kc + h * 32;
                bvB[h][c][0] = *(const f16x8*)(B1 + o);
                bvB[h][c][1] = *(const f16x8*)(B2 + o);
            }
    };
    auto mfmaChunkA = [&]() {
#pragma unroll
        for (int h = 0; h < 2; ++h) {
            f16x8 a1, a2s;
            split2x8(h ? afA1 : afA0, a1, a2s);
#pragma unroll
            for (int c = 0; c < CG; ++c) {
                accM[c] = __builtin_amdgcn_mfma_f32_16x16x32_f16(a1, bvA[h][c][0], accM[c], 0, 0, 0);
                accR[c] = __builtin_amdgcn_mfma_f32_16x16x32_f16(a1, bvA[h][c][1], accR[c], 0, 0, 0);
                accR[c] = __builtin_amdgcn_mfma_f32_16x16x32_f16(a2s, bvA[h][c][0], accR[c], 0, 0, 0);
            }
        }
    };
    auto mfmaChunkB = [&]() {
#pragma unroll
        for (int h = 0; h < 2; ++h) {
            f16x8 a1, a2s;
            split2x8(h ? afB1 : afB0, a1, a2s);
#pragma unroll
            for (int c = 0; c < CG; ++c) {
                accM[c] = __builtin_amdgcn_mfma_f32_16x16x32_f16(a1, bvB[h][c][0], accM[c], 0, 0, 0);
                accR[c] = __builtin_amdgcn_mfma_f32_16x16x32_f16(a1, bvB[h][c][1], accR[c], 0, 0, 0);
                accR[c] = __builtin_amdgcn_mfma_f32_16x16x32_f16(a2s, bvB[h][c][0], accR[c], 0, 0, 0);
            }
        }
    };

    loadChunkA(0);
#pragma unroll
    for (int kc = 0; kc < KLEN; kc += 128) {
        loadChunkB(kc + 64);
        mfmaChunkA();
        if (kc + 128 < KLEN) loadChunkA(kc + 128);
        mfmaChunkB();
    }

    int r0 = row0 + kg * 4;
    float* Pk = P + (size_t)ks * MROWS * N;
#pragma unroll
    for (int c = 0; c < CG; ++c) {
        int col = col0 + c * 16 + lr;
#pragma unroll
        for (int r = 0; r < 4; ++r)
            Pk[(size_t)(r0 + r) * N + col] = accM[c][r] + accR[c][r] * RSCI;
    }
}

// ==== MLP2 GEMM with fused A = gelu(((p0+p1)+(p2+p3)) + bias) ===============
// A-expression identical to R11's add4gelu output (deterministic per elem);
// MFMA order identical to R11 -> bit-identical m2P.
template<int CG, int NKS, int KLEN>
__global__ __launch_bounds__(256) void gemmks_af(
    const float* __restrict__ A,          // m1P plane 0
    const _Float16* __restrict__ B1, const _Float16* __restrict__ B2,
    const float* __restrict__ abias,      // bm[0..1024)
    float* __restrict__ P, int N, int GdivP)
{
    int tid = threadIdx.x, wave = tid >> 6, lane = tid & 63;
    int bid = blockIdx.x;
    int x = bid & 7, inner = bid >> 3;
    int q = inner % GdivP, rowT = inner / GdivP;
    int g = x + 8 * q;
    int colT = g / NKS, ks = g % NKS;

    int lr = lane & 15, kg = lane >> 4;
    int row0 = rowT * 32 + (wave & 1) * 16;
    int col0 = colT * (CG * 32) + (wave >> 1) * (CG * 16);
    int kbase = ks * KLEN;

    const float* Ap = A + (size_t)(row0 + lr) * 1024 + kbase + kg * 8;
    const float* bp = abias + kbase + kg * 8;
    const size_t SPA = (size_t)MROWS * 1024;
    size_t boff = (size_t)(col0 + lr) * 1024 + kbase + kg * 8;

    f32x4 accM[CG], accR[CG];
#pragma unroll
    for (int c = 0; c < CG; ++c) {
        accM[c] = (f32x4){0.f, 0.f, 0.f, 0.f};
        accR[c] = (f32x4){0.f, 0.f, 0.f, 0.f};
    }

    for (int kc = 0; kc < KLEN; kc += 64) {
        f32x8 p00 = *(const f32x8*)(Ap + kc);
        f32x8 p01 = *(const f32x8*)(Ap + SPA + kc);
        f32x8 p02 = *(const f32x8*)(Ap + 2 * SPA + kc);
        f32x8 p03 = *(const f32x8*)(Ap + 3 * SPA + kc);
        f32x8 p10 = *(const f32x8*)(Ap + kc + 32);
        f32x8 p11 = *(const f32x8*)(Ap + SPA + kc + 32);
        f32x8 p12 = *(const f32x8*)(Ap + 2 * SPA + kc + 32);
        f32x8 p13 = *(const f32x8*)(Ap + 3 * SPA + kc + 32);
        f32x8 bv0 = *(const f32x8*)(bp + kc);
        f32x8 bv1 = *(const f32x8*)(bp + kc + 32);
        f32x8 af0, af1;
#pragma unroll
        for (int j = 0; j < 8; ++j) {
            af0[j] = gelu_f(((p00[j] + p01[j]) + (p02[j] + p03[j])) + bv0[j]);
            af1[j] = gelu_f(((p10[j] + p11[j]) + (p12[j] + p13[j])) + bv1[j]);
        }
        f16x8 bv[2][CG][2];
#pragma unroll
        for (int h = 0; h < 2; ++h)
#pragma unroll
            for (int c = 0; c < CG; ++c) {
                size_t o = boff + (size_t)c * 16 * 1024 + kc + h * 32;
                bv[h][c][0] = *(const f16x8*)(B1 + o);
                bv[h][c][1] = *(const f16x8*)(B2 + o);
            }
#pragma unroll
        for (int h = 0; h < 2; ++h) {
            f16x8 a1, a2s;
            split2x8(h ? af1 : af0, a1, a2s);
#pragma unroll
            for (int c = 0; c < CG; ++c) {
                accM[c] = __builtin_amdgcn_mfma_f32_16x16x32_f16(a1, bv[h][c][0], accM[c], 0, 0, 0);
                accR[c] = __builtin_amdgcn_mfma_f32_16x16x32_f16(a1, bv[h][c][1], accR[c], 0, 0, 0);
                accR[c] = __builtin_amdgcn_mfma_f32_16x16x32_f16(a2s, bv[h][c][0], accR[c], 0, 0, 0);
            }
        }
    }

    int r0 = row0 + kg * 4;
    float* Pk = P + (size_t)ks * MROWS * N;
#pragma unroll
    for (int c = 0; c < CG; ++c) {
        int col = col0 + c * 16 + lr;
#pragma unroll
        for (int r = 0; r < 4; ++r)
            Pk[(size_t)(r0 + r) * N + col] = accM[c][r] + accR[c][r] * RSCI;
    }
}

// combine 4 qkv partials + bias over cols [0,3072) -> qkvgC[288][3072]
// (identical expression to R11's add4 restricted to attn columns)
__global__ __launch_bounds__(256) void add4q(
    const float* __restrict__ P, const float* __restrict__ bias,
    float* __restrict__ out)
{
    int idx = blockIdx.x * 256 + threadIdx.x;          // 288*3072/4 = 221184
    if (idx >= MROWS * 3072 / 4) return;
    int row = idx / 768, cq = (idx % 768) * 4;
    size_t SP = (size_t)MROWS * 5120;
    size_t e = (size_t)row * 5120 + cq;
    f32x4 p0 = *(const f32x4*)(P + e);
    f32x4 p1 = *(const f32x4*)(P + SP + e);
    f32x4 p2 = *(const f32x4*)(P + 2 * SP + e);
    f32x4 p3 = *(const f32x4*)(P + 3 * SP + e);
    f32x4 bv = *(const f32x4*)(bias + cq);
    f32x4 s;
#pragma unroll
    for (int j = 0; j < 4; ++j)
        s[j] = ((p0[j] + p1[j]) + (p2[j] + p3[j])) + bv[j];
    *(f32x4*)(out + (size_t)row * 3072 + cq) = s;
}

// ---- direct fp16-split2 GEMM (prep only): one 16x64 wave tile ----
__global__ __launch_bounds__(256) void gemm2(
    const float* __restrict__ A,
    const _Float16* __restrict__ B1, const _Float16* __restrict__ B2,
    const float* __restrict__ bias, float* __restrict__ C, int ldc, int act)
{
    int wave = threadIdx.x >> 6, lane = threadIdx.x & 63;
    int row0 = blockIdx.y * 32 + (wave >> 1) * 16;
    int col0 = blockIdx.x * 128 + (wave & 1) * 64;
    int lr = lane & 15, kofs = (lane >> 4) * 8;
    const float* Ap = A + (size_t)(row0 + lr) * 1024 + kofs;
    size_t boff = (size_t)(col0 + lr) * 1024 + kofs;
    f32x4 accM[4], accR[4];
#pragma unroll
    for (int c = 0; c < 4; ++c) {
        accM[c] = (f32x4){0.f, 0.f, 0.f, 0.f};
        accR[c] = (f32x4){0.f, 0.f, 0.f, 0.f};
    }
    for (int k = 0; k < 1024; k += 32) {
        f32x8 af = *(const f32x8*)(Ap + k);
        f16x8 a1, a2s;
        split2x8(af, a1, a2s);
#pragma unroll
        for (int c = 0; c < 4; ++c) {
            size_t o = boff + (size_t)c * 16 * 1024 + k;
            f16x8 b1 = *(const f16x8*)(B1 + o);
            f16x8 b2 = *(const f16x8*)(B2 + o);
            accM[c] = __builtin_amdgcn_mfma_f32_16x16x32_f16(a1, b1, accM[c], 0, 0, 0);
            accR[c] = __builtin_amdgcn_mfma_f32_16x16x32_f16(a1, b2, accR[c], 0, 0, 0);
            accR[c] = __builtin_amdgcn_mfma_f32_16x16x32_f16(a2s, b1, accR[c], 0, 0, 0);
        }
    }
    int r0 = row0 + (lane >> 4) * 4;
#pragma unroll
    for (int c = 0; c < 4; ++c) {
        int col = col0 + c * 16 + lr;
        float bv = bias ? bias[col] : 0.f;
#pragma unroll
        for (int r = 0; r < 4; ++r) {
            float v = accM[c][r] + accR[c][r] * RSCI + bv;
            if (act == 1) v = gelu_f(v);
            C[(size_t)(r0 + r) * ldc + col] = v;
        }
    }
}

// ---- weight transpose + fp16 split-2: planes[N,1024] from in[1024,N]^T ----
__global__ __launch_bounds__(256) void transpose_split(
    const float* __restrict__ in,
    _Float16* __restrict__ o1, _Float16* __restrict__ o2, int N)
{
    __shared__ float t[32][33];
    int tx = threadIdx.x & 31, ty = threadIdx.x >> 5;
    int k0 = blockIdx.y * 32, n0 = blockIdx.x * 32;
#pragma unroll
    for (int i = 0; i < 4; ++i)
        t[ty + i * 8][tx] = in[(size_t)(k0 + ty + i * 8) * N + n0 + tx];
    __syncthreads();
#pragma unroll
    for (int i = 0; i < 4; ++i) {
        float v = t[tx][ty + i * 8];
        size_t off = (size_t)(n0 + ty + i * 8) * 1024 + k0 + tx;
        split2(v, o1 + off, o2 + off);
    }
}

// ---------------- tiny fp32 GEMM (one-time rproj) ----------------
#define BKK 16
__global__ __launch_bounds__(256) void gemm_f32(
    const float* __restrict__ A, const float* __restrict__ B,
    float* __restrict__ C, int M, int N, int K)
{
    __shared__ float As[BKK][65];
    __shared__ float Bs[BKK][64];
    int tid = threadIdx.x;
    int row0 = blockIdx.y * 64, col0 = blockIdx.x * 64;
    int ty = tid >> 4, tx = tid & 15;
    float acc[4][4];
#pragma unroll
    for (int i = 0; i < 4; ++i)
#pragma unroll
        for (int j = 0; j < 4; ++j) acc[i][j] = 0.f;
    for (int k0 = 0; k0 < K; k0 += BKK) {
        {
            int r = tid >> 2, kv = (tid & 3) * 4;
            float4 v = make_float4(0.f, 0.f, 0.f, 0.f);
            int gr = row0 + r;
            if (gr < M) v = *(const float4*)(A + (size_t)gr * K + k0 + kv);
            As[kv + 0][r] = v.x; As[kv + 1][r] = v.y;
            As[kv + 2][r] = v.z; As[kv + 3][r] = v.w;
        }
        {
            int r = tid >> 4, cv = (tid & 15) * 4;
            float4 v = *(const float4*)(B + (size_t)(k0 + r) * N + col0 + cv);
            *(float4*)&Bs[r][cv] = v;
        }
        __syncthreads();
#pragma unroll
        for (int kk = 0; kk < BKK; ++kk) {
            float a[4], b[4];
#pragma unroll
            for (int j = 0; j < 4; ++j) a[j] = As[kk][ty * 4 + j];
#pragma unroll
            for (int j = 0; j < 4; ++j) b[j] = Bs[kk][tx * 4 + j];
#pragma unroll
            for (int i = 0; i < 4; ++i)
#pragma unroll
                for (int j = 0; j < 4; ++j) acc[i][j] += a[i] * b[j];
        }
        __syncthreads();
    }
#pragma unroll
    for (int i = 0; i < 4; ++i) {
        int gr = row0 + ty * 4 + i;
        if (gr >= M) continue;
#pragma unroll
        for (int j = 0; j < 4; ++j)
            C[(size_t)gr * N + col0 + tx * 4 + j] = acc[i][j];
    }
}

// ---------------- relative embedding table ----------------
__global__ void relemb_kernel(float* __restrict__ tab)
{
    int p = blockIdx.x;
    float pv = (float)(p - MM);
    for (int i = threadIdx.x; i < UU; i += blockDim.x) {
        float expo = (float)(i & ~1) * (1.0f / (float)UU);
        float scale = exp2f(-expo * 13.287712379549449f);  // 10000^-expo
        float ang = pv * scale;
        tab[p * UU + i] = (i & 1) ? cosf(ang) : sinf(ang);
    }
}

// ---------------- init mp ----------------
__global__ void init_mp(const float* __restrict__ xp_all, float* __restrict__ mp)
{
    int row = blockIdx.x;                 // 0..287
    int b = row / LL, l = row % LL;
    for (int u = threadIdx.x; u < UU; u += blockDim.x)
        mp[(size_t)row * UU + u] = (l == MM) ? xp_all[((size_t)b * TT) * UU + u] : 0.f;
}

// ---------------- attention + LN1 (reads compact qkvgC[288][3072]) ----------
__global__ __launch_bounds__(512) void attn_ln(
    const float* __restrict__ qkvgC, const float* __restrict__ rproj,
    const float* __restrict__ mp,
    const float* __restrict__ gamma, const float* __restrict__ beta,
    float* __restrict__ a1)
{
    __shared__ float sA[LL][UU];
    __shared__ float red[16];
    int b = blockIdx.x;
    int tid = threadIdx.x;
    int wave = tid >> 6, lane = tid & 63;

    for (int hh = 0; hh < 2; ++hh) {
        int h = wave + hh * 8;
        const float* base = qkvgC + (size_t)b * LL * 3072 + h * 64 + lane;
        float q[LL], k[LL], v[LL], r[RR];
#pragma unroll
        for (int l = 0; l < LL; ++l) {
            q[l] = base[l * 3072];
            k[l] = base[l * 3072 + 1024];
            v[l] = base[l * 3072 + 2048];
        }
#pragma unroll
        for (int rp = 0; rp < RR; ++rp) r[rp] = rproj[rp * UU + h * 64 + lane];
#pragma unroll
        for (int qr = 0; qr < LL; ++qr) {
            float sc[LL];
#pragma unroll
            for (int kr = 0; kr < LL; ++kr) {
                float prod = q[qr] * (k[kr] + r[qr - kr + MM]);
#pragma unroll
                for (int o = 32; o > 0; o >>= 1) prod += __shfl_xor(prod, o);
                sc[kr] = prod * 0.125f;
            }
            float m = sc[0];
#pragma unroll
            for (int kr = 1; kr < LL; ++kr) m = fmaxf(m, sc[kr]);
            float s = 0.f;
#pragma unroll
            for (int kr = 0; kr < LL; ++kr) { sc[kr] = expf(sc[kr] - m); s += sc[kr]; }
            float inv = 1.0f / s;
            float acc = 0.f;
#pragma unroll
            for (int kr = 0; kr < LL; ++kr) acc += sc[kr] * v[kr];
            sA[qr][h * 64 + lane] = acc * inv;
        }
    }
    __syncthreads();

    for (int l = 0; l < LL; ++l) {
        size_t row = (size_t)(b * LL + l);
        float x0 = mp[row * UU + tid] + sA[l][tid];
        float x1 = mp[row * UU + tid + 512] + sA[l][tid + 512];
        float s = x0 + x1, ss = x0 * x0 + x1 * x1;
#pragma unroll
        for (int o = 32; o > 0; o >>= 1) { s += __shfl_xor(s, o); ss += __shfl_xor(ss, o); }
        if (lane == 0) { red[wave * 2] = s; red[wave * 2 + 1] = ss; }
        __syncthreads();
        float S = 0.f, SS = 0.f;
#pragma unroll
        for (int w = 0; w < 8; ++w) { S += red[w * 2]; SS += red[w * 2 + 1]; }
        __syncthreads();
        float mean = S * (1.0f / UU);
        float var = SS * (1.0f / UU) - mean * mean;
        float rstd = rsqrtf(var + 1e-6f);
        a1[row * UU + tid]       = (x0 - mean) * rstd * gamma[tid] + beta[tid];
        a1[row * UU + tid + 512] = (x1 - mean) * rstd * gamma[tid + 512] + beta[tid + 512];
    }
}

// ------- finalize: m2 combine + gate 4-plane combine + LN2 + update ---------
// gate expression ((p0+p1)+(p2+p3))+b1 identical to R11's add4 output.
__global__ __launch_bounds__(256) void finalize_step(
    const float* __restrict__ a1, const float* __restrict__ m2P,
    const float* __restrict__ bm,
    const float* __restrict__ qkvgP, const float* __restrict__ b1,
    const float* __restrict__ gx_all,
    const float* __restrict__ xp_all,
    const float* __restrict__ gamma, const float* __restrict__ beta,
    float* __restrict__ mp, float* __restrict__ out, int t)
{
    __shared__ float red[8];
    int row = blockIdx.x;                 // 0..287
    int b = row / LL, l = row % LL;
    int tid = threadIdx.x;
    int wave = tid >> 6, lane = tid & 63;
    const size_t SP = (size_t)MROWS * UU;
    const size_t SPA = (size_t)MROWS * 5120;

    float x[4];
    float s = 0.f, ss = 0.f;
#pragma unroll
    for (int j = 0; j < 4; ++j) {
        int u = tid + j * 256;
        size_t off = (size_t)row * UU + u;
        float m2v = ((m2P[off] + m2P[SP + off]) + (m2P[2 * SP + off] + m2P[3 * SP + off]))
                    + bm[1024 + u];
        x[j] = a1[off] + m2v;
        s += x[j]; ss += x[j] * x[j];
    }
#pragma unroll
    for (int o = 32; o > 0; o >>= 1) { s += __shfl_xor(s, o); ss += __shfl_xor(ss, o); }
    if (lane == 0) { red[wave * 2] = s; red[wave * 2 + 1] = ss; }
    __syncthreads();
    float S = 0.f, SS = 0.f;
#pragma unroll
    for (int w = 0; w < 4; ++w) { S += red[w * 2]; SS += red[w * 2 + 1]; }
    float mean = S * (1.0f / UU);
    float rstd = rsqrtf(SS * (1.0f / UU) - mean * mean + 1e-6f);

    size_t gxoff = ((size_t)b * TT + t) * 2048;
    size_t grow = (size_t)row * 5120 + 3072;
#pragma unroll
    for (int j = 0; j < 4; ++j) {
        int u = tid + j * 256;
        float cand = (x[j] - mean) * rstd * gamma[1024 + u] + beta[1024 + u];
        float tc = tanhf(cand);
        float qgi = ((qkvgP[grow + u] + qkvgP[SPA + grow + u])
                     + (qkvgP[2 * SPA + grow + u] + qkvgP[3 * SPA + grow + u]))
                    + b1[3072 + u];
        float qgf = ((qkvgP[grow + 1024 + u] + qkvgP[SPA + grow + 1024 + u])
                     + (qkvgP[2 * SPA + grow + 1024 + u] + qkvgP[3 * SPA + grow + 1024 + u]))
                    + b1[4096 + u];
        float gi = gx_all[gxoff + u]        + qgi;
        float gf = gx_all[gxoff + 1024 + u] + qgf;
        float ig = fminf(fmaxf(0.2f * gi + 0.5f, 0.f), 1.f);
        float fg = fminf(fmaxf(0.2f * (gf + 1.0f) + 0.5f, 0.f), 1.f);
        size_t off = (size_t)row * UU + u;
        float nmp = fg * mp[off] + ig * tc;
        if (l < MM) {
            mp[off] = nmp;
        } else {
            out[((size_t)b * TT + t) * UU + u] = nmp;
            if (t + 1 < TT)
                mp[off] = xp_all[((size_t)b * TT + t + 1) * UU + u];
        }
    }
}

// ---------------- host launcher ----------------
extern "C" void kernel_launch(void* const* d_in, const int* in_sizes, int n_in,
                              void* d_out, int out_size, void* d_ws, size_t ws_size,
                              hipStream_t stream)
{
    const float* x    = (const float*)d_in[0];
    const float* Wi   = (const float*)d_in[1];
    const float* bi   = (const float*)d_in[2];
    const float* Wg   = (const float*)d_in[3];
    const float* Wr   = (const float*)d_in[4];
    const float* br   = (const float*)d_in[5];
    const float* Wa   = (const float*)d_in[6];
    const float* ba   = (const float*)d_in[7];
    const float* Wm   = (const float*)d_in[8];
    const float* bm   = (const float*)d_in[9];
    const float* gam  = (const float*)d_in[10];
    const float* bet  = (const float*)d_in[11];
    const float* Wrel = (const float*)d_in[12];
    float* out = (float*)d_out;

    // ---- workspace layout ----
    char* w = (char*)d_ws;
    float*  xp_all = (float*)w;  w += (size_t)BB*TT*UU*4;        // 16.8 MB
    float*  gx_all = (float*)w;  w += (size_t)BB*TT*2048*4;      // 33.6 MB
    size_t W1N = (size_t)5120 * 1024, WMN = (size_t)2048 * 1024;
    _Float16* W1a = (_Float16*)w;  w += W1N*2;                   // 10.5 MB
    _Float16* W1b = (_Float16*)w;  w += W1N*2;                   // 10.5 MB
    _Float16* Wma = (_Float16*)w;  w += WMN*2;                   // 4.2 MB
    _Float16* Wmb = (_Float16*)w;  w += WMN*2;                   // 4.2 MB
    float*  b1    = (float*)w;   w += 5120*4;
    float*  tab   = (float*)w;   w += RR*UU*4;
    float*  rproj = (float*)w;   w += RR*UU*4;
    float*  mp    = (float*)w;   w += (size_t)MROWS*UU*4;
    float*  a1    = (float*)w;   w += (size_t)MROWS*UU*4;
    float*  qkvgC = (float*)w;   w += (size_t)MROWS*3072*4;      // 3.5 MB
    // partials (qkvgP region aliased by prep-only Wi/Wg planes)
    char* sbase = w;
    float*  qkvgP = (float*)w;   w += (size_t)4*MROWS*5120*4;    // 23.6 MB
    float*  m1P   = (float*)w;   w += (size_t)4*MROWS*UU*4;      // 4.7 MB
    float*  m2P   = (float*)w;   w += (size_t)4*MROWS*UU*4;      // 4.7 MB
    _Float16* Wia = (_Float16*)sbase;
    _Float16* Wib = Wia + (size_t)1024 * 1024;
    _Float16* Wga = Wib + (size_t)1024 * 1024;
    _Float16* Wgb = Wga + (size_t)2048 * 1024;   // ends at 12.6 MB < 23.6 MB ✓

    // ---- one-time prep ----
    relemb_kernel<<<RR, 256, 0, stream>>>(tab);
    gemm_f32<<<dim3(UU / 64, 1), 256, 0, stream>>>(tab, Wrel, rproj, RR, UU, UU);
    transpose_split<<<dim3(3072 / 32, 32), 256, 0, stream>>>(Wa, W1a, W1b, 3072);
    transpose_split<<<dim3(2048 / 32, 32), 256, 0, stream>>>(
        Wr, W1a + (size_t)3072 * 1024, W1b + (size_t)3072 * 1024, 2048);
    transpose_split<<<dim3(2048 / 32, 32), 256, 0, stream>>>(Wm, Wma, Wmb, 2048);
    transpose_split<<<dim3(1024 / 32, 32), 256, 0, stream>>>(Wi, Wia, Wib, 1024);
    transpose_split<<<dim3(2048 / 32, 32), 256, 0, stream>>>(Wg, Wga, Wgb, 2048);
    hipMemcpyAsync(b1, ba, 3072 * sizeof(float), hipMemcpyDeviceToDevice, stream);
    hipMemcpyAsync(b1 + 3072, br, 2048 * sizeof(float), hipMemcpyDeviceToDevice, stream);
    gemm2<<<dim3(UU / 128, (BB * TT) / 32), 256, 0, stream>>>(
        x, Wia, Wib, bi, xp_all, UU, 0);
    gemm2<<<dim3(2048 / 128, (BB * TT) / 32), 256, 0, stream>>>(
        x, Wga, Wgb, nullptr, gx_all, 2048, 0);
    init_mp<<<MROWS, 256, 0, stream>>>(xp_all, mp);

    // ---- sequential scan (6 dispatches/step; all expressions == R11) ----
    // phase A: CG=2, NKS=4, KLEN=256: ncolT=80, g=320, GdivP=40, blocks=2880
    // MLPs:    CG=2, NKS=4, KLEN=256: ncolT=16, g=64,  GdivP=8,  blocks=576
    for (int t = 0; t < TT; ++t) {
        gemmks<2, 4, 256><<<2880, 256, 0, stream>>>(mp, W1a, W1b, qkvgP, 5120, 40);
        add4q<<<864, 256, 0, stream>>>(qkvgP, b1, qkvgC);
        attn_ln<<<BB, 512, 0, stream>>>(qkvgC, rproj, mp, gam, bet, a1);
        gemmks<2, 4, 256><<<576, 256, 0, stream>>>(a1, Wma, Wmb, m1P, UU, 8);
        gemmks_af<2, 4, 256><<<576, 256, 0, stream>>>(
            m1P, Wma + (size_t)1024 * 1024, Wmb + (size_t)1024 * 1024, bm,
            m2P, UU, 8);
        finalize_step<<<MROWS, 256, 0, stream>>>(a1, m2P, bm, qkvgP, b1, gx_all,
                                                 xp_all, gam, bet, mp, out, t);
    }
}

// Round 16
// 20890.739 us; speedup vs baseline: 1.0904x; 1.0904x over previous
//
#include <hip/hip_runtime.h>
#include <hip/hip_bf16.h>
#include <math.h>

// Problem config (fixed)
#define BB 32      // batch
#define TT 128     // time steps
#define UU 1024    // units
#define MM 8       // memory slots
#define LL 9       // M+1
#define RR 17      // 2M+1
#define MROWS 288  // BB*LL
#define RSC 4096.0f          // residual plane scale (2^12)
#define RSCI (1.0f/4096.0f)

typedef _Float16 f16x8 __attribute__((ext_vector_type(8)));
typedef float f32x4 __attribute__((ext_vector_type(4)));
typedef float f32x8 __attribute__((ext_vector_type(8)));

// fp16 split-2 with scaled residual: v ~= h1 + h2/4096, |err| <= 2^-22|v|
__device__ __forceinline__ void split2(float v, _Float16* h1, _Float16* h2)
{
    _Float16 a = (_Float16)v;
    float r = (v - (float)a) * RSC;
    *h1 = a; *h2 = (_Float16)r;
}

__device__ __forceinline__ void split2x8(const f32x8 v, f16x8& a, f16x8& b)
{
#pragma unroll
    for (int j = 0; j < 8; ++j) {
        float f = v[j];
        _Float16 h1 = (_Float16)f;
        float r = (f - (float)h1) * RSC;
        a[j] = h1; b[j] = (_Float16)r;
    }
}

__device__ __forceinline__ float gelu_f(float x)
{
    float t = tanhf(0.7978845608028654f * (x + 0.044715f * x * x * x));
    return 0.5f * x * (1.f + t);
}

// ================= K-split fp16-split2 MFMA GEMM (no LDS, no barriers) ======
// Partial[ks][MROWS][N] = A[MROWS, kslice] @ Bt[N, kslice]^T, kslice = KLEN.
// B given as plane1 (fp16) + plane2 (fp16, x4096). 3 MFMAs per fragment:
// accM += a1*b1 ; accR += a1*b2s + a2s*b1 ; result = accM + accR/4096.
// Block 256 thr = 4 waves in 2x2; wave tile 16 rows x CG*16 cols.
// bid = (g&7) + 8*(q + GdivP*rowT): same-B-slice blocks share an XCD.
template<int CG, int NKS, int KLEN>
__global__ __launch_bounds__(256) void gemmks(
    const float* __restrict__ A,
    const _Float16* __restrict__ B1, const _Float16* __restrict__ B2,
    float* __restrict__ P, int N, int GdivP)
{
    int tid = threadIdx.x, wave = tid >> 6, lane = tid & 63;
    int bid = blockIdx.x;
    int x = bid & 7, inner = bid >> 3;
    int q = inner % GdivP, rowT = inner / GdivP;
    int g = x + 8 * q;
    int colT = g / NKS, ks = g % NKS;

    int lr = lane & 15, kg = lane >> 4;
    int row0 = rowT * 32 + (wave & 1) * 16;
    int col0 = colT * (CG * 32) + (wave >> 1) * (CG * 16);
    int kbase = ks * KLEN;

    const float* Ap = A + (size_t)(row0 + lr) * 1024 + kbase + kg * 8;
    size_t boff = (size_t)(col0 + lr) * 1024 + kbase + kg * 8;

    f32x4 accM[CG], accR[CG];
#pragma unroll
    for (int c = 0; c < CG; ++c) {
        accM[c] = (f32x4){0.f, 0.f, 0.f, 0.f};
        accR[c] = (f32x4){0.f, 0.f, 0.f, 0.f};
    }

    for (int kc = 0; kc < KLEN; kc += 64) {
        // issue all loads for this 64-k chunk first (independent)
        f32x8 af0 = *(const f32x8*)(Ap + kc);
        f32x8 af1 = *(const f32x8*)(Ap + kc + 32);
        f16x8 bv[2][CG][2];
#pragma unroll
        for (int h = 0; h < 2; ++h)
#pragma unroll
            for (int c = 0; c < CG; ++c) {
                size_t o = boff + (size_t)c * 16 * 1024 + kc + h * 32;
                bv[h][c][0] = *(const f16x8*)(B1 + o);
                bv[h][c][1] = *(const f16x8*)(B2 + o);
            }
#pragma unroll
        for (int h = 0; h < 2; ++h) {
            f16x8 a1, a2s;
            split2x8(h ? af1 : af0, a1, a2s);
#pragma unroll
            for (int c = 0; c < CG; ++c) {
                accM[c] = __builtin_amdgcn_mfma_f32_16x16x32_f16(a1, bv[h][c][0], accM[c], 0, 0, 0);
                accR[c] = __builtin_amdgcn_mfma_f32_16x16x32_f16(a1, bv[h][c][1], accR[c], 0, 0, 0);
                accR[c] = __builtin_amdgcn_mfma_f32_16x16x32_f16(a2s, bv[h][c][0], accR[c], 0, 0, 0);
            }
        }
    }

    int r0 = row0 + kg * 4;
    float* Pk = P + (size_t)ks * MROWS * N;
#pragma unroll
    for (int c = 0; c < CG; ++c) {
        int col = col0 + c * 16 + lr;
#pragma unroll
        for (int r = 0; r < 4; ++r)
            Pk[(size_t)(r0 + r) * N + col] = accM[c][r] + accR[c][r] * RSCI;
    }
}

// combine 4 K-split partials + bias (+optional gelu)
__global__ __launch_bounds__(256) void add4(
    const float* __restrict__ P, const float* __restrict__ bias,
    float* __restrict__ out, int N, int act, int total4)
{
    int idx = blockIdx.x * 256 + threadIdx.x;
    if (idx >= total4) return;
    size_t e = (size_t)idx * 4;
    size_t SP = (size_t)MROWS * N;
    int col = (int)(e % N);
    f32x4 p0 = *(const f32x4*)(P + e);
    f32x4 p1 = *(const f32x4*)(P + SP + e);
    f32x4 p2 = *(const f32x4*)(P + 2 * SP + e);
    f32x4 p3 = *(const f32x4*)(P + 3 * SP + e);
    f32x4 bv = *(const f32x4*)(bias + col);
    f32x4 s;
#pragma unroll
    for (int j = 0; j < 4; ++j) {
        float v = ((p0[j] + p1[j]) + (p2[j] + p3[j])) + bv[j];
        s[j] = act ? gelu_f(v) : v;
    }
    *(f32x4*)(out + e) = s;
}

// ---- direct fp16-split2 GEMM (prep only): one 16x64 wave tile ----
__global__ __launch_bounds__(256) void gemm2(
    const float* __restrict__ A,
    const _Float16* __restrict__ B1, const _Float16* __restrict__ B2,
    const float* __restrict__ bias, float* __restrict__ C, int ldc, int act)
{
    int wave = threadIdx.x >> 6, lane = threadIdx.x & 63;
    int row0 = blockIdx.y * 32 + (wave >> 1) * 16;
    int col0 = blockIdx.x * 128 + (wave & 1) * 64;
    int lr = lane & 15, kofs = (lane >> 4) * 8;
    const float* Ap = A + (size_t)(row0 + lr) * 1024 + kofs;
    size_t boff = (size_t)(col0 + lr) * 1024 + kofs;
    f32x4 accM[4], accR[4];
#pragma unroll
    for (int c = 0; c < 4; ++c) {
        accM[c] = (f32x4){0.f, 0.f, 0.f, 0.f};
        accR[c] = (f32x4){0.f, 0.f, 0.f, 0.f};
    }
    for (int k = 0; k < 1024; k += 32) {
        f32x8 af = *(const f32x8*)(Ap + k);
        f16x8 a1, a2s;
        split2x8(af, a1, a2s);
#pragma unroll
        for (int c = 0; c < 4; ++c) {
            size_t o = boff + (size_t)c * 16 * 1024 + k;
            f16x8 b1 = *(const f16x8*)(B1 + o);
            f16x8 b2 = *(const f16x8*)(B2 + o);
            accM[c] = __builtin_amdgcn_mfma_f32_16x16x32_f16(a1, b1, accM[c], 0, 0, 0);
            accR[c] = __builtin_amdgcn_mfma_f32_16x16x32_f16(a1, b2, accR[c], 0, 0, 0);
            accR[c] = __builtin_amdgcn_mfma_f32_16x16x32_f16(a2s, b1, accR[c], 0, 0, 0);
        }
    }
    int r0 = row0 + (lane >> 4) * 4;
#pragma unroll
    for (int c = 0; c < 4; ++c) {
        int col = col0 + c * 16 + lr;
        float bv = bias ? bias[col] : 0.f;
#pragma unroll
        for (int r = 0; r < 4; ++r) {
            float v = accM[c][r] + accR[c][r] * RSCI + bv;
            if (act == 1) v = gelu_f(v);
            C[(size_t)(r0 + r) * ldc + col] = v;
        }
    }
}

// ---- weight transpose + fp16 split-2: planes[N,1024] from in[1024,N]^T ----
__global__ __launch_bounds__(256) void transpose_split(
    const float* __restrict__ in,
    _Float16* __restrict__ o1, _Float16* __restrict__ o2, int N)
{
    __shared__ float t[32][33];
    int tx = threadIdx.x & 31, ty = threadIdx.x >> 5;
    int k0 = blockIdx.y * 32, n0 = blockIdx.x * 32;
#pragma unroll
    for (int i = 0; i < 4; ++i)
        t[ty + i * 8][tx] = in[(size_t)(k0 + ty + i * 8) * N + n0 + tx];
    __syncthreads();
#pragma unroll
    for (int i = 0; i < 4; ++i) {
        float v = t[tx][ty + i * 8];
        size_t off = (size_t)(n0 + ty + i * 8) * 1024 + k0 + tx;
        split2(v, o1 + off, o2 + off);
    }
}

// ---------------- tiny fp32 GEMM (one-time rproj) ----------------
#define BKK 16
__global__ __launch_bounds__(256) void gemm_f32(
    const float* __restrict__ A, const float* __restrict__ B,
    float* __restrict__ C, int M, int N, int K)
{
    __shared__ float As[BKK][65];
    __shared__ float Bs[BKK][64];
    int tid = threadIdx.x;
    int row0 = blockIdx.y * 64, col0 = blockIdx.x * 64;
    int ty = tid >> 4, tx = tid & 15;
    float acc[4][4];
#pragma unroll
    for (int i = 0; i < 4; ++i)
#pragma unroll
        for (int j = 0; j < 4; ++j) acc[i][j] = 0.f;
    for (int k0 = 0; k0 < K; k0 += BKK) {
        {
            int r = tid >> 2, kv = (tid & 3) * 4;
            float4 v = make_float4(0.f, 0.f, 0.f, 0.f);
            int gr = row0 + r;
            if (gr < M) v = *(const float4*)(A + (size_t)gr * K + k0 + kv);
            As[kv + 0][r] = v.x; As[kv + 1][r] = v.y;
            As[kv + 2][r] = v.z; As[kv + 3][r] = v.w;
        }
        {
            int r = tid >> 4, cv = (tid & 15) * 4;
            float4 v = *(const float4*)(B + (size_t)(k0 + r) * N + col0 + cv);
            *(float4*)&Bs[r][cv] = v;
        }
        __syncthreads();
#pragma unroll
        for (int kk = 0; kk < BKK; ++kk) {
            float a[4], b[4];
#pragma unroll
            for (int j = 0; j < 4; ++j) a[j] = As[kk][ty * 4 + j];
#pragma unroll
            for (int j = 0; j < 4; ++j) b[j] = Bs[kk][tx * 4 + j];
#pragma unroll
            for (int i = 0; i < 4; ++i)
#pragma unroll
                for (int j = 0; j < 4; ++j) acc[i][j] += a[i] * b[j];
        }
        __syncthreads();
    }
#pragma unroll
    for (int i = 0; i < 4; ++i) {
        int gr = row0 + ty * 4 + i;
        if (gr >= M) continue;
#pragma unroll
        for (int j = 0; j < 4; ++j)
            C[(size_t)gr * N + col0 + tx * 4 + j] = acc[i][j];
    }
}

// ---------------- relative embedding table ----------------
__global__ void relemb_kernel(float* __restrict__ tab)
{
    int p = blockIdx.x;
    float pv = (float)(p - MM);
    for (int i = threadIdx.x; i < UU; i += blockDim.x) {
        float expo = (float)(i & ~1) * (1.0f / (float)UU);
        float scale = exp2f(-expo * 13.287712379549449f);  // 10000^-expo
        float ang = pv * scale;
        tab[p * UU + i] = (i & 1) ? cosf(ang) : sinf(ang);
    }
}

// ---------------- init mp ----------------
__global__ void init_mp(const float* __restrict__ xp_all, float* __restrict__ mp)
{
    int row = blockIdx.x;                 // 0..287
    int b = row / LL, l = row % LL;
    for (int u = threadIdx.x; u < UU; u += blockDim.x)
        mp[(size_t)row * UU + u] = (l == MM) ? xp_all[((size_t)b * TT) * UU + u] : 0.f;
}

// ---------------- attention + LN1 (one block per batch element) ----------------
__global__ __launch_bounds__(512) void attn_ln(
    const float* __restrict__ qkvg, const float* __restrict__ rproj,
    const float* __restrict__ mp,
    const float* __restrict__ gamma, const float* __restrict__ beta,
    float* __restrict__ a1)
{
    __shared__ float sA[LL][UU];
    __shared__ float red[16];
    int b = blockIdx.x;
    int tid = threadIdx.x;
    int wave = tid >> 6, lane = tid & 63;

    for (int hh = 0; hh < 2; ++hh) {
        int h = wave + hh * 8;
        const float* base = qkvg + (size_t)b * LL * 5120 + h * 64 + lane;
        float q[LL], k[LL], v[LL], r[RR];
#pragma unroll
        for (int l = 0; l < LL; ++l) {
            q[l] = base[l * 5120];
            k[l] = base[l * 5120 + 1024];
            v[l] = base[l * 5120 + 2048];
        }
#pragma unroll
        for (int rp = 0; rp < RR; ++rp) r[rp] = rproj[rp * UU + h * 64 + lane];
#pragma unroll
        for (int qr = 0; qr < LL; ++qr) {
            float sc[LL];
#pragma unroll
            for (int kr = 0; kr < LL; ++kr) {
                float prod = q[qr] * (k[kr] + r[qr - kr + MM]);
#pragma unroll
                for (int o = 32; o > 0; o >>= 1) prod += __shfl_xor(prod, o);
                sc[kr] = prod * 0.125f;
            }
            float m = sc[0];
#pragma unroll
            for (int kr = 1; kr < LL; ++kr) m = fmaxf(m, sc[kr]);
            float s = 0.f;
#pragma unroll
            for (int kr = 0; kr < LL; ++kr) { sc[kr] = expf(sc[kr] - m); s += sc[kr]; }
            float inv = 1.0f / s;
            float acc = 0.f;
#pragma unroll
            for (int kr = 0; kr < LL; ++kr) acc += sc[kr] * v[kr];
            sA[qr][h * 64 + lane] = acc * inv;
        }
    }
    __syncthreads();

    for (int l = 0; l < LL; ++l) {
        size_t row = (size_t)(b * LL + l);
        float x0 = mp[row * UU + tid] + sA[l][tid];
        float x1 = mp[row * UU + tid + 512] + sA[l][tid + 512];
        float s = x0 + x1, ss = x0 * x0 + x1 * x1;
#pragma unroll
        for (int o = 32; o > 0; o >>= 1) { s += __shfl_xor(s, o); ss += __shfl_xor(ss, o); }
        if (lane == 0) { red[wave * 2] = s; red[wave * 2 + 1] = ss; }
        __syncthreads();
        float S = 0.f, SS = 0.f;
#pragma unroll
        for (int w = 0; w < 8; ++w) { S += red[w * 2]; SS += red[w * 2 + 1]; }
        __syncthreads();
        float mean = S * (1.0f / UU);
        float var = SS * (1.0f / UU) - mean * mean;
        float rstd = rsqrtf(var + 1e-6f);
        a1[row * UU + tid]       = (x0 - mean) * rstd * gamma[tid] + beta[tid];
        a1[row * UU + tid + 512] = (x1 - mean) * rstd * gamma[tid + 512] + beta[tid + 512];
    }
}

// ------- finalize: combine m2 partials + LN2 + gates + memory update --------
__global__ __launch_bounds__(256) void finalize_step(
    const float* __restrict__ a1, const float* __restrict__ m2P,
    const float* __restrict__ bm,
    const float* __restrict__ qkvg, const float* __restrict__ gx_all,
    const float* __restrict__ xp_all,
    const float* __restrict__ gamma, const float* __restrict__ beta,
    float* __restrict__ mp, float* __restrict__ out, int t)
{
    __shared__ float red[8];
    int row = blockIdx.x;                 // 0..287
    int b = row / LL, l = row % LL;
    int tid = threadIdx.x;
    int wave = tid >> 6, lane = tid & 63;
    const size_t SP = (size_t)MROWS * UU;

    float x[4];
    float s = 0.f, ss = 0.f;
#pragma unroll
    for (int j = 0; j < 4; ++j) {
        int u = tid + j * 256;
        size_t off = (size_t)row * UU + u;
        float m2v = ((m2P[off] + m2P[SP + off]) + (m2P[2 * SP + off] + m2P[3 * SP + off]))
                    + bm[1024 + u];
        x[j] = a1[off] + m2v;
        s += x[j]; ss += x[j] * x[j];
    }
#pragma unroll
    for (int o = 32; o > 0; o >>= 1) { s += __shfl_xor(s, o); ss += __shfl_xor(ss, o); }
    if (lane == 0) { red[wave * 2] = s; red[wave * 2 + 1] = ss; }
    __syncthreads();
    float S = 0.f, SS = 0.f;
#pragma unroll
    for (int w = 0; w < 4; ++w) { S += red[w * 2]; SS += red[w * 2 + 1]; }
    float mean = S * (1.0f / UU);
    float rstd = rsqrtf(SS * (1.0f / UU) - mean * mean + 1e-6f);

    size_t gxoff = ((size_t)b * TT + t) * 2048;
    size_t grow = (size_t)row * 5120 + 3072;
#pragma unroll
    for (int j = 0; j < 4; ++j) {
        int u = tid + j * 256;
        float cand = (x[j] - mean) * rstd * gamma[1024 + u] + beta[1024 + u];
        float tc = tanhf(cand);
        float gi = gx_all[gxoff + u]        + qkvg[grow + u];
        float gf = gx_all[gxoff + 1024 + u] + qkvg[grow + 1024 + u];
        float ig = fminf(fmaxf(0.2f * gi + 0.5f, 0.f), 1.f);
        float fg = fminf(fmaxf(0.2f * (gf + 1.0f) + 0.5f, 0.f), 1.f);
        size_t off = (size_t)row * UU + u;
        float nmp = fg * mp[off] + ig * tc;
        if (l < MM) {
            mp[off] = nmp;
        } else {
            out[((size_t)b * TT + t) * UU + u] = nmp;
            if (t + 1 < TT)
                mp[off] = xp_all[((size_t)b * TT + t + 1) * UU + u];
        }
    }
}

// ---------------- host launcher ----------------
extern "C" void kernel_launch(void* const* d_in, const int* in_sizes, int n_in,
                              void* d_out, int out_size, void* d_ws, size_t ws_size,
                              hipStream_t stream)
{
    const float* x    = (const float*)d_in[0];
    const float* Wi   = (const float*)d_in[1];
    const float* bi   = (const float*)d_in[2];
    const float* Wg   = (const float*)d_in[3];
    const float* Wr   = (const float*)d_in[4];
    const float* br   = (const float*)d_in[5];
    const float* Wa   = (const float*)d_in[6];
    const float* ba   = (const float*)d_in[7];
    const float* Wm   = (const float*)d_in[8];
    const float* bm   = (const float*)d_in[9];
    const float* gam  = (const float*)d_in[10];
    const float* bet  = (const float*)d_in[11];
    const float* Wrel = (const float*)d_in[12];
    float* out = (float*)d_out;

    // ---- workspace layout ----
    char* w = (char*)d_ws;
    float*  xp_all = (float*)w;  w += (size_t)BB*TT*UU*4;        // 16.8 MB
    float*  gx_all = (float*)w;  w += (size_t)BB*TT*2048*4;      // 33.6 MB
    size_t W1N = (size_t)5120 * 1024, WMN = (size_t)2048 * 1024;
    _Float16* W1a = (_Float16*)w;  w += W1N*2;                   // 10.5 MB
    _Float16* W1b = (_Float16*)w;  w += W1N*2;                   // 10.5 MB
    _Float16* Wma = (_Float16*)w;  w += WMN*2;                   // 4.2 MB
    _Float16* Wmb = (_Float16*)w;  w += WMN*2;                   // 4.2 MB
    float*  b1    = (float*)w;   w += 5120*4;
    float*  tab   = (float*)w;   w += RR*UU*4;
    float*  rproj = (float*)w;   w += RR*UU*4;
    float*  mp    = (float*)w;   w += (size_t)MROWS*UU*4;
    float*  qkvg  = (float*)w;   w += (size_t)MROWS*5120*4;      // 5.9 MB
    float*  a1    = (float*)w;   w += (size_t)MROWS*UU*4;
    float*  hbuf  = (float*)w;   w += (size_t)MROWS*UU*4;
    // partials (qkvgP region aliased by prep-only Wi/Wg planes)
    char* sbase = w;
    float*  qkvgP = (float*)w;   w += (size_t)4*MROWS*5120*4;    // 23.6 MB
    float*  m1P   = (float*)w;   w += (size_t)4*MROWS*UU*4;      // 4.7 MB
    float*  m2P   = (float*)w;   w += (size_t)4*MROWS*UU*4;      // 4.7 MB
    _Float16* Wia = (_Float16*)sbase;
    _Float16* Wib = Wia + (size_t)1024 * 1024;
    _Float16* Wga = Wib + (size_t)1024 * 1024;
    _Float16* Wgb = Wga + (size_t)2048 * 1024;   // ends at 12.6 MB < 23.6 MB ✓

    // ---- one-time prep ----
    relemb_kernel<<<RR, 256, 0, stream>>>(tab);
    gemm_f32<<<dim3(UU / 64, 1), 256, 0, stream>>>(tab, Wrel, rproj, RR, UU, UU);
    transpose_split<<<dim3(3072 / 32, 32), 256, 0, stream>>>(Wa, W1a, W1b, 3072);
    transpose_split<<<dim3(2048 / 32, 32), 256, 0, stream>>>(
        Wr, W1a + (size_t)3072 * 1024, W1b + (size_t)3072 * 1024, 2048);
    transpose_split<<<dim3(2048 / 32, 32), 256, 0, stream>>>(Wm, Wma, Wmb, 2048);
    transpose_split<<<dim3(1024 / 32, 32), 256, 0, stream>>>(Wi, Wia, Wib, 1024);
    transpose_split<<<dim3(2048 / 32, 32), 256, 0, stream>>>(Wg, Wga, Wgb, 2048);
    hipMemcpyAsync(b1, ba, 3072 * sizeof(float), hipMemcpyDeviceToDevice, stream);
    hipMemcpyAsync(b1 + 3072, br, 2048 * sizeof(float), hipMemcpyDeviceToDevice, stream);
    gemm2<<<dim3(UU / 128, (BB * TT) / 32), 256, 0, stream>>>(
        x, Wia, Wib, bi, xp_all, UU, 0);
    gemm2<<<dim3(2048 / 128, (BB * TT) / 32), 256, 0, stream>>>(
        x, Wga, Wgb, nullptr, gx_all, 2048, 0);
    init_mp<<<MROWS, 256, 0, stream>>>(xp_all, mp);

    // ---- sequential scan (7 dispatches/step, R11 structure) ----
    // phase A: CG=2, NKS=4, KLEN=256: ncolT=80, g=320, GdivP=40, blocks=2880
    // MLPs:    CG=2, NKS=4, KLEN=256: ncolT=16, g=64,  GdivP=8,  blocks=576
    for (int t = 0; t < TT; ++t) {
        gemmks<2, 4, 256><<<2880, 256, 0, stream>>>(mp, W1a, W1b, qkvgP, 5120, 40);
        add4<<<(MROWS * 5120 / 4 + 255) / 256, 256, 0, stream>>>(
            qkvgP, b1, qkvg, 5120, 0, MROWS * 5120 / 4);
        attn_ln<<<BB, 512, 0, stream>>>(qkvg, rproj, mp, gam, bet, a1);
        gemmks<2, 4, 256><<<576, 256, 0, stream>>>(a1, Wma, Wmb, m1P, UU, 8);
        add4<<<(MROWS * UU / 4 + 255) / 256, 256, 0, stream>>>(
            m1P, bm, hbuf, UU, 1, MROWS * UU / 4);
        gemmks<2, 4, 256><<<576, 256, 0, stream>>>(hbuf, Wma + (size_t)1024 * 1024,
                                                   Wmb + (size_t)1024 * 1024, m2P, UU, 8);
        finalize_step<<<MROWS, 256, 0, stream>>>(a1, m2P, bm, qkvg, gx_all, xp_all,
                                                 gam, bet, mp, out, t);
    }
}